// Round 18
// baseline (416.309 us; speedup 1.0000x reference)
//
#include <hip/hip_runtime.h>
#include <math.h>

#define D_   256
#define H_   8
#define L_   2
#define FF_  1024
#define S_   512
#define B_   32
#define M_   4096
#define NC_  10
#define ROWS (B_*S_)   // 16384

typedef __attribute__((ext_vector_type(8))) short bf16x8;
typedef __attribute__((ext_vector_type(4))) float f32x4;
typedef unsigned int uint32;

__device__ __forceinline__ float wave_sum(float v) {
#pragma unroll
  for (int off = 1; off < 64; off <<= 1) v += __shfl_xor(v, off, 64);
  return v;
}

__device__ __forceinline__ unsigned short bf16_rne(float x) {
  unsigned int b = __float_as_uint(x);
  return (unsigned short)((b + 0x7FFFu + ((b >> 16) & 1u)) >> 16);
}
__device__ __forceinline__ float bf16_f(unsigned short h) {
  return __uint_as_float(((unsigned int)h) << 16);
}
// split x into hi/lo bf16, packed as hi | (lo<<16)
__device__ __forceinline__ uint32 pack_split(float x) {
  const unsigned short h = bf16_rne(x);
  const unsigned short l = bf16_rne(x - bf16_f(h));
  return (uint32)h | ((uint32)l << 16);
}
// reconstruct fp32 (hi+lo)
__device__ __forceinline__ float unsplit(uint32 p) {
  return __uint_as_float(p << 16) + __uint_as_float(p & 0xffff0000u);
}
// 4 packed elems -> 8B hi-quad + 8B lo-quad into LDS planes
__device__ __forceinline__ void unpack_store(unsigned short* Hq, unsigned short* Lq,
                                             int off, uint4 v) {
  uint2 hp, lp;
  hp.x = (v.x & 0xffffu) | (v.y << 16);
  hp.y = (v.z & 0xffffu) | (v.w << 16);
  lp.x = (v.x >> 16) | (v.y & 0xffff0000u);
  lp.y = (v.z >> 16) | (v.w & 0xffff0000u);
  *(uint2*)&Hq[off] = hp;
  *(uint2*)&Lq[off] = lp;
}
// 8 packed u32 (2 uint4) -> in-register hi/lo bf16x8 (bit-identical to LDS path)
__device__ __forceinline__ void unpack_frag(const uint4 u0, const uint4 u1,
                                            bf16x8* hi, bf16x8* lo) {
  union { uint32 w[4]; bf16x8 v; } H, L;
  H.w[0] = (u0.x & 0xffffu) | (u0.y << 16);
  H.w[1] = (u0.z & 0xffffu) | (u0.w << 16);
  H.w[2] = (u1.x & 0xffffu) | (u1.y << 16);
  H.w[3] = (u1.z & 0xffffu) | (u1.w << 16);
  L.w[0] = (u0.x >> 16) | (u0.y & 0xffff0000u);
  L.w[1] = (u0.z >> 16) | (u0.w & 0xffff0000u);
  L.w[2] = (u1.x >> 16) | (u1.y & 0xffff0000u);
  L.w[3] = (u1.z >> 16) | (u1.w & 0xffff0000u);
  *hi = H.v; *lo = L.v;
}
// b64-pair fragment load (rows at 72B/1032B stride)
__device__ __forceinline__ bf16x8 ld_frag(const unsigned short* p, int off) {
  union { uint2 u[2]; bf16x8 v; } x;
  x.u[0] = *(const uint2*)(p + off);
  x.u[1] = *(const uint2*)(p + off + 4);
  return x.v;
}

// ---- weight fragment packing (read-coalesced): W[N][K] -> frag-major u32 ---
// Fragment (nf,kt): lane l holds (n=nf*16+(l&15), k=kt*32+(l>>4)*8+j);
// j=0..3 uint4 at frag*512+l*4, j=4..7 at +256. Each thread reads one
// CONTIGUOUS row-major float4 and writes one uint4 to its frag slot.
__global__ __launch_bounds__(256) void pack_wfrag(const float* __restrict__ W,
                                                  uint32* __restrict__ dst,
                                                  int N, int K) {
  const int i = blockIdx.x * 256 + threadIdx.x;
  if (i >= N * K / 4) return;
  const int flat = i * 4;
  const int n = flat / K, k = flat - (flat / K) * K;  // k is 4-aligned
  const float4 v = *(const float4*)(W + (size_t)n * K + k);
  uint4 o;
  o.x = pack_split(v.x); o.y = pack_split(v.y);
  o.z = pack_split(v.z); o.w = pack_split(v.w);
  const int ktiles = K >> 5;
  const int frag = (n >> 4) * ktiles + (k >> 5);
  const int lane = (n & 15) + 16 * ((k & 31) >> 3);
  const int hi = ((k & 7) >= 4) ? 256 : 0;
  *(uint4*)(dst + (size_t)frag * 512 + lane * 4 + hi) = o;
}

// ---------------- embedding (packed only) -----------------------------------
__global__ __launch_bounds__(256) void emb_kernel(const int* __restrict__ ids,
                                                  const float* __restrict__ tok,
                                                  const float* __restrict__ pos,
                                                  uint32* __restrict__ xp) {
  const int row  = blockIdx.x * 4 + (threadIdx.x >> 6);
  const int lane = threadIdx.x & 63;
  const int id = ids[row];
  const int s  = row & (S_ - 1);
  const float4 t = *(const float4*)(tok + (size_t)id * D_ + lane * 4);
  const float4 p = *(const float4*)(pos + (size_t)s  * D_ + lane * 4);
  uint4 o;
  o.x = pack_split(t.x + p.x); o.y = pack_split(t.y + p.y);
  o.z = pack_split(t.z + p.z); o.w = pack_split(t.w + p.w);
  *(uint4*)(xp + (size_t)row * D_ + lane * 4) = o;
}

// ---- split-bf16 MFMA GEMM v4: 128x128 block, 4 waves of 64x64 -------------
// A staged in LDS (coalescing layer); B loaded DIRECT from frag-packed global
// (coalesced 1KB/frag, L2-resident weights). LDS halved -> higher ceiling.
#define LP 36
template<int RELU>
__global__ __launch_bounds__(256, 2) void gemm_mfma(const uint32* __restrict__ Ap,
                                                    const uint32* __restrict__ Wf,
                                                    const float* __restrict__ bias,
                                                    uint32* __restrict__ Cp,
                                                    int K, int N, int NX) {
  __shared__ __align__(16) unsigned short Ah[128 * LP];
  __shared__ __align__(16) unsigned short Al[128 * LP];

  const int q8 = gridDim.x >> 3;
  const int orig = (blockIdx.x & 7) * q8 + (blockIdx.x >> 3);
  const int by = orig / NX, bx = orig % NX;
  const int m0 = by * 128, n0 = bx * 128;

  const int tid  = threadIdx.x;
  const int lane = tid & 63;
  const int wid  = tid >> 6;        // 0..3
  const int wm = wid >> 1, wn = wid & 1;
  const int lrow  = lane & 15;
  const int khalf = (lane >> 4) * 8;

  const int srow = tid >> 3;        // 0..31 (+j*32)
  const int kq   = (tid & 7) << 2;
  const uint32* Aptr = Ap + (size_t)(m0 + srow) * K + kq;

  const int ktiles = K >> 5;
  size_t fbase[4];
#pragma unroll
  for (int f = 0; f < 4; f++)
    fbase[f] = (size_t)(((n0 + wn * 64 + f * 16) >> 4) * ktiles) * 512 + lane * 4;

  f32x4 acc[4][4];
#pragma unroll
  for (int i = 0; i < 4; i++)
#pragma unroll
    for (int j = 0; j < 4; j++) acc[i][j] = (f32x4){0.f, 0.f, 0.f, 0.f};

  uint4 pa[4];
#pragma unroll
  for (int j = 0; j < 4; j++) pa[j] = *(const uint4*)(Aptr + (size_t)j * 32 * K);

  for (int k0 = 0; k0 < K; k0 += 32) {
    uint4 b0[4], b1[4];
#pragma unroll
    for (int f = 0; f < 4; f++) {
      const uint32* fb = Wf + fbase[f] + (size_t)(k0 >> 5) * 512;
      b0[f] = *(const uint4*)fb;
      b1[f] = *(const uint4*)(fb + 256);
    }
    const int kn = (k0 + 32 < K) ? (k0 + 32) : k0;
    uint4 na[4];
#pragma unroll
    for (int j = 0; j < 4; j++)
      na[j] = *(const uint4*)(Aptr + (size_t)j * 32 * K + kn);

    __syncthreads();
#pragma unroll
    for (int j = 0; j < 4; j++)
      unpack_store(Ah, Al, (srow + j * 32) * LP + kq, pa[j]);
    __syncthreads();

    bf16x8 ah[4], al[4], bh[4], bl[4];
#pragma unroll
    for (int f = 0; f < 4; f++) {
      const int rA = (wm * 64 + f * 16 + lrow) * LP + khalf;
      ah[f] = ld_frag(Ah, rA);
      al[f] = ld_frag(Al, rA);
      unpack_frag(b0[f], b1[f], &bh[f], &bl[f]);
    }
#pragma unroll
    for (int fm = 0; fm < 4; fm++)
#pragma unroll
      for (int fn = 0; fn < 4; fn++) {
        acc[fm][fn] = __builtin_amdgcn_mfma_f32_16x16x32_bf16(ah[fm], bh[fn], acc[fm][fn], 0, 0, 0);
        acc[fm][fn] = __builtin_amdgcn_mfma_f32_16x16x32_bf16(ah[fm], bl[fn], acc[fm][fn], 0, 0, 0);
        acc[fm][fn] = __builtin_amdgcn_mfma_f32_16x16x32_bf16(al[fm], bh[fn], acc[fm][fn], 0, 0, 0);
      }
#pragma unroll
    for (int j = 0; j < 4; j++) pa[j] = na[j];
  }

#pragma unroll
  for (int fm = 0; fm < 4; fm++)
#pragma unroll
    for (int fn = 0; fn < 4; fn++) {
      const int mrow = m0 + wm * 64 + fm * 16 + (lane >> 4) * 4;
      const int ncol = n0 + wn * 64 + fn * 16 + (lane & 15);
      const float bi = bias[ncol];
#pragma unroll
      for (int r = 0; r < 4; r++) {
        float v = acc[fm][fn][r] + bi;
        if (RELU) v = fmaxf(v, 0.f);
        Cp[(size_t)(mrow + r) * N + ncol] = pack_split(v);
      }
    }
}

// ---- fused full-row GEMM v4 (N=256): 64x256 block, 8 waves of 32x64 -------
// A staged in LDS; B direct from frag-packed global.
// MODE 0: bias + residual(packed) + LayerNorm -> packed out.
// MODE 1: bias + ReLU + gate dot -> mask.
template<int MODE>
__global__ __launch_bounds__(512, 2) void gemm_ln(const uint32* __restrict__ Ap,
                                                  const uint32* __restrict__ Wf,
                                                  const float* __restrict__ bias,
                                                  const uint32* __restrict__ residP,
                                                  const float* __restrict__ g,
                                                  const float* __restrict__ beta,
                                                  const float* __restrict__ Wg2,
                                                  const float* __restrict__ bg2,
                                                  uint32* __restrict__ outP,
                                                  int* __restrict__ mask,
                                                  int K) {
  __shared__ __align__(16) unsigned short Ah[64 * LP];
  __shared__ __align__(16) unsigned short Al[64 * LP];
  __shared__ float psumS[4][64];
  __shared__ float psumQ[4][64];
  __shared__ float meanL[64];
  __shared__ float invL[64];

  const int q8 = gridDim.x >> 3;
  const int m0 = ((blockIdx.x & 7) * q8 + (blockIdx.x >> 3)) * 64;

  const int tid  = threadIdx.x;
  const int lane = tid & 63;
  const int wid  = tid >> 6;       // 0..7
  const int wm = wid >> 2, wn = wid & 3;
  const int lrow  = lane & 15;
  const int khalf = (lane >> 4) * 8;

  const int srow = tid >> 3;            // 0..63
  const int kq   = (tid & 7) << 2;
  const uint32* Aptr = Ap + (size_t)(m0 + srow) * K + kq;

  const int ktiles = K >> 5;
  size_t fbase[4];
#pragma unroll
  for (int f = 0; f < 4; f++)
    fbase[f] = (size_t)(((wn * 64 + f * 16) >> 4) * ktiles) * 512 + lane * 4;

  f32x4 acc[2][4];
#pragma unroll
  for (int i = 0; i < 2; i++)
#pragma unroll
    for (int j = 0; j < 4; j++) acc[i][j] = (f32x4){0.f, 0.f, 0.f, 0.f};

  uint4 pa = *(const uint4*)Aptr;

  for (int k0 = 0; k0 < K; k0 += 32) {
    uint4 b0[4], b1[4];
#pragma unroll
    for (int f = 0; f < 4; f++) {
      const uint32* fb = Wf + fbase[f] + (size_t)(k0 >> 5) * 512;
      b0[f] = *(const uint4*)fb;
      b1[f] = *(const uint4*)(fb + 256);
    }
    const int kn = (k0 + 32 < K) ? (k0 + 32) : k0;
    uint4 na = *(const uint4*)(Aptr + kn);

    __syncthreads();
    unpack_store(Ah, Al, srow * LP + kq, pa);
    __syncthreads();

    bf16x8 ah[2], al[2], bh[4], bl[4];
#pragma unroll
    for (int fm = 0; fm < 2; fm++) {
      const int r = (wm * 32 + fm * 16 + lrow) * LP + khalf;
      ah[fm] = ld_frag(Ah, r);
      al[fm] = ld_frag(Al, r);
    }
#pragma unroll
    for (int fn = 0; fn < 4; fn++)
      unpack_frag(b0[fn], b1[fn], &bh[fn], &bl[fn]);
#pragma unroll
    for (int fm = 0; fm < 2; fm++)
#pragma unroll
      for (int fn = 0; fn < 4; fn++) {
        acc[fm][fn] = __builtin_amdgcn_mfma_f32_16x16x32_bf16(ah[fm], bh[fn], acc[fm][fn], 0, 0, 0);
        acc[fm][fn] = __builtin_amdgcn_mfma_f32_16x16x32_bf16(ah[fm], bl[fn], acc[fm][fn], 0, 0, 0);
        acc[fm][fn] = __builtin_amdgcn_mfma_f32_16x16x32_bf16(al[fm], bh[fn], acc[fm][fn], 0, 0, 0);
      }
    pa = na;
  }

  // ---- epilogue: full row (256 cols) resident in block ----
  int cc[4];
  float bi[4];
#pragma unroll
  for (int fn = 0; fn < 4; fn++) {
    cc[fn] = wn * 64 + fn * 16 + (lane & 15);
    bi[fn] = bias[cc[fn]];
  }

  float vv[2][4][4];
  float rs[2][4], rq[2][4];

  if (MODE == 0) {
#pragma unroll
    for (int fm = 0; fm < 2; fm++)
#pragma unroll
      for (int r = 0; r < 4; r++) {
        const int row = m0 + wm * 32 + fm * 16 + (lane >> 4) * 4 + r;
        float s = 0.f, q = 0.f;
#pragma unroll
        for (int fn = 0; fn < 4; fn++) {
          const float rx = unsplit(residP[(size_t)row * 256 + cc[fn]]);
          const float a = acc[fm][fn][r] + bi[fn] + rx;
          vv[fm][fn][r] = a;
          s += a; q += a * a;
        }
        rs[fm][r] = s; rq[fm][r] = q;
      }
  } else {
    float wg[4];
#pragma unroll
    for (int fn = 0; fn < 4; fn++) wg[fn] = Wg2[cc[fn]];
#pragma unroll
    for (int fm = 0; fm < 2; fm++)
#pragma unroll
      for (int r = 0; r < 4; r++) {
        float s = 0.f;
#pragma unroll
        for (int fn = 0; fn < 4; fn++)
          s += fmaxf(acc[fm][fn][r] + bi[fn], 0.f) * wg[fn];
        rs[fm][r] = s;
      }
  }

#pragma unroll
  for (int off = 1; off < 16; off <<= 1) {
#pragma unroll
    for (int fm = 0; fm < 2; fm++)
#pragma unroll
      for (int r = 0; r < 4; r++) {
        rs[fm][r] += __shfl_xor(rs[fm][r], off, 64);
        if (MODE == 0) rq[fm][r] += __shfl_xor(rq[fm][r], off, 64);
      }
  }
  if ((lane & 15) == 0) {
#pragma unroll
    for (int fm = 0; fm < 2; fm++)
#pragma unroll
      for (int r = 0; r < 4; r++) {
        const int rloc = wm * 32 + fm * 16 + (lane >> 4) * 4 + r;
        psumS[wn][rloc] = rs[fm][r];
        if (MODE == 0) psumQ[wn][rloc] = rq[fm][r];
      }
  }
  __syncthreads();
  if (tid < 64) {
    float s = 0.f, q = 0.f;
#pragma unroll
    for (int w = 0; w < 4; w++) {
      s += psumS[w][tid];
      if (MODE == 0) q += psumQ[w][tid];
    }
    if (MODE == 0) {
      const float mean = s * (1.f / 256.f);
      const float var = q * (1.f / 256.f) - mean * mean;
      meanL[tid] = mean;
      invL[tid] = rsqrtf(var + 1e-5f);
    } else {
      mask[m0 + tid] = (s + bg2[0]) > 0.f ? 1 : 0;
    }
  }
  if (MODE == 0) {
    __syncthreads();
#pragma unroll
    for (int fm = 0; fm < 2; fm++)
#pragma unroll
      for (int r = 0; r < 4; r++) {
        const int rloc = wm * 32 + fm * 16 + (lane >> 4) * 4 + r;
        const int row = m0 + rloc;
        const float mu = meanL[rloc], iv = invL[rloc];
#pragma unroll
        for (int fn = 0; fn < 4; fn++) {
          const float y = (vv[fm][fn][r] - mu) * iv * g[cc[fn]] + beta[cc[fn]];
          outP[(size_t)row * 256 + cc[fn]] = pack_split(y);
        }
      }
  }
}

// ---------------- MFMA attention (monolithic stage, 2-tile pipeline) --------
#define KP 36    // u16/row: 72B stride
#define VP 516   // u16/row: 1032B stride
__global__ __launch_bounds__(1024, 4) void attn_mfma(const uint32* __restrict__ qkv,
                                                     uint32* __restrict__ o) {
  __shared__ __align__(16) unsigned short Kh[512 * KP];
  __shared__ __align__(16) unsigned short Kl[512 * KP];
  __shared__ __align__(16) unsigned short Vth[32 * VP];
  __shared__ __align__(16) unsigned short Vtl[32 * VP];

  const int q8g = gridDim.x >> 3;                 // 32
  const int obh = (blockIdx.x & 7) * q8g + (blockIdx.x >> 3);
  const int b = obh >> 3, h = obh & 7;
  const int tid = threadIdx.x;
  const int lane = tid & 63;
  const int wv = tid >> 6;
  const uint32* base = qkv + (size_t)b * (S_ * 768) + h * 32;

  if (tid < 512) {
    const int slot = tid;
    const int s5 = slot & 31;
    const int orig = (slot & ~31) + 8 * ((s5 >> 2) & 3) + ((s5 >> 4) << 2) + (s5 & 3);
    const uint32* p = base + (size_t)orig * 768 + 256;
#pragma unroll
    for (int j = 0; j < 8; j++)
      unpack_store(Kh, Kl, slot * KP + j * 4, *(const uint4*)(p + j * 4));
  } else {
    const int u  = tid - 512;
    const int kp = u & 255;
    const int dg = (u >> 8) * 16;
    const uint32* p0 = base + (size_t)(2 * kp) * 768 + 512 + dg;
    const uint32* p1 = p0 + 768;
    union { uint4 u4[4]; uint32 w[16]; } a0, a1;
#pragma unroll
    for (int i = 0; i < 4; i++) {
      a0.u4[i] = *(const uint4*)(p0 + i * 4);
      a1.u4[i] = *(const uint4*)(p1 + i * 4);
    }
#pragma unroll
    for (int d = 0; d < 16; d++) {
      const uint32 w0 = a0.w[d], w1 = a1.w[d];
      *(uint32*)&Vth[(dg + d) * VP + 2 * kp] = (w0 & 0xffffu) | (w1 << 16);
      *(uint32*)&Vtl[(dg + d) * VP + 2 * kp] = (w0 >> 16) | (w1 & 0xffff0000u);
    }
  }

  const int q0 = wv * 32;
  bf16x8 qh[2], ql[2];
#pragma unroll
  for (int f = 0; f < 2; f++) {
    const uint32* qp = base + (size_t)(q0 + f * 16 + (lane & 15)) * 768 + ((lane >> 4) * 8);
    union { uint4 u4[2]; uint32 w[8]; } qu;
    qu.u4[0] = *(const uint4*)qp;
    qu.u4[1] = *(const uint4*)(qp + 4);
    bf16x8 vh, vl;
#pragma unroll
    for (int j = 0; j < 8; j++) {
      const float qf = unsplit(qu.w[j]);
      const float sv = qf * 0.17677669529663687f;
      const unsigned short hh = bf16_rne(sv);
      vh[j] = (short)hh;
      vl[j] = (short)bf16_rne(sv - bf16_f(hh));
    }
    qh[f] = vh; ql[f] = vl;
  }

  __syncthreads();

  auto qk_tile = [&](int kt, f32x4 (&s)[2][2]) {
    bf16x8 kah[2], kal[2];
#pragma unroll
    for (int u = 0; u < 2; u++) {
      const int off = (kt + u * 16 + (lane & 15)) * KP + ((lane >> 4) * 8);
      kah[u] = ld_frag(Kh, off);
      kal[u] = ld_frag(Kl, off);
    }
#pragma unroll
    for (int u = 0; u < 2; u++)
#pragma unroll
      for (int f = 0; f < 2; f++) {
        f32x4 a = (f32x4){0.f, 0.f, 0.f, 0.f};
        a = __builtin_amdgcn_mfma_f32_16x16x32_bf16(kal[u], qh[f], a, 0, 0, 0);
        a = __builtin_amdgcn_mfma_f32_16x16x32_bf16(kah[u], ql[f], a, 0, 0, 0);
        a = __builtin_amdgcn_mfma_f32_16x16x32_bf16(kah[u], qh[f], a, 0, 0, 0);
        s[u][f] = a;
      }
  };

  f32x4 oacc[2][2];
#pragma unroll
  for (int i = 0; i < 2; i++)
#pragma unroll
    for (int j = 0; j < 2; j++) oacc[i][j] = (f32x4){0.f, 0.f, 0.f, 0.f};
  float lacc[2] = {0.f, 0.f};

  f32x4 sA[2][2], sB[2][2];
  qk_tile(0, sA);

  for (int kt = 0; kt < S_; kt += 32) {
    if (kt + 32 < S_) qk_tile(kt + 32, sB);

    bf16x8 vah[2], val[2];
#pragma unroll
    for (int df = 0; df < 2; df++) {
      const int off = (df * 16 + (lane & 15)) * VP + kt + ((lane >> 4) * 8);
      vah[df] = ld_frag(Vth, off);
      val[df] = ld_frag(Vtl, off);
    }
#pragma unroll
    for (int f = 0; f < 2; f++) {
      union { uint32 w[4]; bf16x8 v; } ph, pl;
#pragma unroll
      for (int u = 0; u < 2; u++) {
        const float p0 = __expf(sA[u][f][0]);
        const float p1 = __expf(sA[u][f][1]);
        const float p2 = __expf(sA[u][f][2]);
        const float p3 = __expf(sA[u][f][3]);
        lacc[f] += (p0 + p1) + (p2 + p3);
        unsigned int h01, h23;
        asm volatile("v_cvt_pk_bf16_f32 %0, %1, %2" : "=v"(h01) : "v"(p0), "v"(p1));
        asm volatile("v_cvt_pk_bf16_f32 %0, %1, %2" : "=v"(h23) : "v"(p2), "v"(p3));
        const float r0 = p0 - __uint_as_float(h01 << 16);
        const float r1 = p1 - __uint_as_float(h01 & 0xffff0000u);
        const float r2 = p2 - __uint_as_float(h23 << 16);
        const float r3 = p3 - __uint_as_float(h23 & 0xffff0000u);
        unsigned int l01, l23;
        asm volatile("v_cvt_pk_bf16_f32 %0, %1, %2" : "=v"(l01) : "v"(r0), "v"(r1));
        asm volatile("v_cvt_pk_bf16_f32 %0, %1, %2" : "=v"(l23) : "v"(r2), "v"(r3));
        ph.w[u * 2 + 0] = h01;
        ph.w[u * 2 + 1] = h23;
        pl.w[u * 2 + 0] = l01;
        pl.w[u * 2 + 1] = l23;
      }
#pragma unroll
      for (int df = 0; df < 2; df++) {
        oacc[df][f] = __builtin_amdgcn_mfma_f32_16x16x32_bf16(val[df], ph.v, oacc[df][f], 0, 0, 0);
        oacc[df][f] = __builtin_amdgcn_mfma_f32_16x16x32_bf16(vah[df], pl.v, oacc[df][f], 0, 0, 0);
        oacc[df][f] = __builtin_amdgcn_mfma_f32_16x16x32_bf16(vah[df], ph.v, oacc[df][f], 0, 0, 0);
      }
    }
    if (kt + 32 < S_) {
#pragma unroll
      for (int u = 0; u < 2; u++)
#pragma unroll
        for (int f = 0; f < 2; f++) sA[u][f] = sB[u][f];
    }
  }

#pragma unroll
  for (int f = 0; f < 2; f++) {
    lacc[f] += __shfl_xor(lacc[f], 16, 64);
    lacc[f] += __shfl_xor(lacc[f], 32, 64);
  }
#pragma unroll
  for (int f = 0; f < 2; f++) {
    const float inv = 1.f / lacc[f];
    const int q = q0 + f * 16 + (lane & 15);
    uint32* op = o + (size_t)(b * S_ + q) * D_ + h * 32;
#pragma unroll
    for (int df = 0; df < 2; df++) {
      const int dbase = df * 16 + (lane >> 4) * 4;
#pragma unroll
      for (int r = 0; r < 4; r++)
        op[dbase + r] = pack_split(oacc[df][f][r] * inv);
    }
  }
}

// -------- parallel prefix-scan over 16384 masks (sequential semantics) ------
__global__ __launch_bounds__(256) void scan_kernel(const int* __restrict__ mask,
                                                   int* __restrict__ slots,
                                                   int* __restrict__ countp) {
  __shared__ int wtot[4];
  const int tid = threadIdx.x;
  const int lane = tid & 63, wid = tid >> 6;
  const int base = tid * 64;
  int s = 0;
#pragma unroll 8
  for (int i = 0; i < 64; i++) s += mask[base + i];
  int inc = s;
#pragma unroll
  for (int off = 1; off < 64; off <<= 1) {
    const int t = __shfl_up(inc, off, 64);
    if (lane >= off) inc += t;
  }
  if (lane == 63) wtot[wid] = inc;
  __syncthreads();
  int woff = 0;
#pragma unroll
  for (int w = 0; w < 4; w++) woff += (w < wid) ? wtot[w] : 0;
  const int total = wtot[0] + wtot[1] + wtot[2] + wtot[3];
  if (tid == 0) countp[0] = total < M_ ? total : M_;
  int run = woff + inc - s;
  for (int i = 0; i < 64; i++) {
    const int r = base + i;
    const int mk = mask[r];
    slots[r] = (mk && run < M_) ? run : -1;
    run += mk;
  }
}

// ---------------- scatter selected rows into memory (packed h -> fp32 mem) --
__global__ __launch_bounds__(256) void scatter_kernel(const uint32* __restrict__ h,
                                                      const int* __restrict__ slots,
                                                      float* __restrict__ mem) {
  const int row  = blockIdx.x * 4 + (threadIdx.x >> 6);
  const int lane = threadIdx.x & 63;
  const int sl = slots[row];
  if (sl >= 0) {
    const uint4 p = *(const uint4*)(h + (size_t)row * D_ + lane * 4);
    float4 r;
    r.x = unsplit(p.x); r.y = unsplit(p.y);
    r.z = unsplit(p.z); r.w = unsplit(p.w);
    *(float4*)(mem + (size_t)sl * D_ + lane * 4) = r;
  }
}

// ---------------- query norms (one wave per batch row, packed h) ------------
__global__ __launch_bounds__(256) void qnorm_kernel(const uint32* __restrict__ h,
                                                    float* __restrict__ qden) {
  const int b    = blockIdx.x * 4 + (threadIdx.x >> 6);
  const int lane = threadIdx.x & 63;
  const uint4 p = *(const uint4*)(h + (size_t)b * S_ * D_ + lane * 4);
  const float x0 = unsplit(p.x), x1 = unsplit(p.y);
  const float x2 = unsplit(p.z), x3 = unsplit(p.w);
  float sq = x0 * x0 + x1 * x1 + x2 * x2 + x3 * x3;
  sq = wave_sum(sq);
  if (lane == 0) qden[b] = sqrtf(sq) + 1e-8f;
}

// ------- sims[b][r] for all 32 b: one wave per memory row r -----------------
__global__ __launch_bounds__(256) void sims_kernel(const uint32* __restrict__ h,
                                                   const float* __restrict__ mem,
                                                   const float* __restrict__ qden,
                                                   const int* __restrict__ countp,
                                                   float* __restrict__ sims) {
  __shared__ float cls[B_ * D_];
  __shared__ float qd[B_];
  const int tid = threadIdx.x;
  const int lane = tid & 63, wid = tid >> 6;
  for (int i = tid; i < B_ * D_ / 4; i += 256) {
    const int flat = i * 4;
    const int b = flat >> 8, d = flat & 255;
    const uint4 p = *(const uint4*)(h + (size_t)b * S_ * D_ + d);
    float4 r;
    r.x = unsplit(p.x); r.y = unsplit(p.y);
    r.z = unsplit(p.z); r.w = unsplit(p.w);
    *(float4*)&cls[flat] = r;
  }
  if (tid < B_) qd[tid] = qden[tid];
  __syncthreads();
  const int count = countp[0];
  const int r = blockIdx.x * 4 + wid;
  const float4 m4 = *(const float4*)(mem + (size_t)r * D_ + lane * 4);
  float sq = m4.x * m4.x + m4.y * m4.y + m4.z * m4.z + m4.w * m4.w;
  sq = wave_sum(sq);
  const float rn = sqrtf(sq) + 1e-8f;
  if (r < count) {
    for (int b = 0; b < B_; b++) {
      const float4 c4 = *(const float4*)&cls[b * D_ + lane * 4];
      float dt = m4.x * c4.x + m4.y * c4.y + m4.z * c4.z + m4.w * c4.w;
      dt = wave_sum(dt);
      if (lane == 0) sims[b * M_ + r] = dt / (qd[b] * rn);
    }
  } else if (lane == 0) {
    for (int b = 0; b < B_; b++) sims[b * M_ + r] = -1e9f;
  }
}

// ---------------- per-batch: top-4 (wave-parallel argmax), mix, classifier --
__global__ __launch_bounds__(256) void topk_mix(const uint32* __restrict__ h,
                                                const float* __restrict__ mem,
                                                const float* __restrict__ simsg,
                                                const int* __restrict__ countp,
                                                const float* __restrict__ Wc,
                                                const float* __restrict__ bc,
                                                float* __restrict__ out) {
  __shared__ float sims[M_];
  __shared__ float cls[D_];
  __shared__ float wv4[4];
  __shared__ int   wi4[4];
  __shared__ float aug[D_];
  __shared__ float tv[4];
  __shared__ int   tix[4];

  const int b = blockIdx.x, tid = threadIdx.x;
  const int lane = tid & 63, wid = tid >> 6;
  const int count = countp[0];

  for (int i = tid; i < M_; i += 256) sims[i] = simsg[b * M_ + i];
  cls[tid] = unsplit(h[(size_t)b * S_ * D_ + tid]);
  __syncthreads();

  for (int k = 0; k < 4; k++) {
    float bv = -INFINITY; int bi = 1 << 30;
#pragma unroll
    for (int rr = 0; rr < M_ / 256; rr++) {
      const int r = tid + rr * 256;
      const float v = sims[r];
      if (v > bv || (v == bv && r < bi)) { bv = v; bi = r; }
    }
#pragma unroll
    for (int off = 1; off < 64; off <<= 1) {
      const float ov = __shfl_xor(bv, off, 64);
      const int   oi = __shfl_xor(bi, off, 64);
      if (ov > bv || (ov == bv && oi < bi)) { bv = ov; bi = oi; }
    }
    if (lane == 0) { wv4[wid] = bv; wi4[wid] = bi; }
    __syncthreads();
    if (tid == 0) {
      float bb = wv4[0]; int bbi = wi4[0];
#pragma unroll
      for (int i = 1; i < 4; i++)
        if (wv4[i] > bb || (wv4[i] == bb && wi4[i] < bbi)) { bb = wv4[i]; bbi = wi4[i]; }
      tv[k] = bb; tix[k] = bbi; sims[bbi] = -INFINITY;
    }
    __syncthreads();
  }

  float w[4];
  {
    const float mx = tv[0];
    float ws = 0.f;
#pragma unroll
    for (int k = 0; k < 4; k++) { w[k] = expf(tv[k] - mx); ws += w[k]; }
    const float inv = 1.f / ws;
#pragma unroll
    for (int k = 0; k < 4; k++) w[k] *= inv;
  }

  {
    float mv = 0.f;
    if (count > 0) {
#pragma unroll
      for (int k = 0; k < 4; k++) mv = fmaf(w[k], mem[(size_t)tix[k] * D_ + tid], mv);
    }
    aug[tid] = cls[tid] + mv;
  }
  __syncthreads();

  const float4 a4 = *(const float4*)&aug[lane * 4];
  for (int c = wid; c < NC_; c += 4) {
    const float4 wc = *(const float4*)(Wc + (size_t)c * D_ + lane * 4);
    float dt = a4.x * wc.x + a4.y * wc.y + a4.z * wc.z + a4.w * wc.w;
    dt = wave_sum(dt);
    if (lane == 0) out[b * NC_ + c] = dt + bc[c];
  }
}

// ---------------- launcher ---------------------------------------------------
extern "C" void kernel_launch(void* const* d_in, const int* in_sizes, int n_in,
                              void* d_out, int out_size, void* d_ws, size_t ws_size,
                              hipStream_t stream) {
  const int*   ids  = (const int*)d_in[0];
  const float* tok  = (const float*)d_in[1];
  const float* pos  = (const float*)d_in[2];
  const float* Wqkv = (const float*)d_in[3];
  const float* bqkv = (const float*)d_in[4];
  const float* Wo   = (const float*)d_in[5];
  const float* bo   = (const float*)d_in[6];
  const float* ln1g = (const float*)d_in[7];
  const float* ln1b = (const float*)d_in[8];
  const float* W1   = (const float*)d_in[9];
  const float* b1   = (const float*)d_in[10];
  const float* W2   = (const float*)d_in[11];
  const float* b2   = (const float*)d_in[12];
  const float* ln2g = (const float*)d_in[13];
  const float* ln2b = (const float*)d_in[14];
  const float* Wg1  = (const float*)d_in[15];
  const float* bg1  = (const float*)d_in[16];
  const float* Wg2  = (const float*)d_in[17];
  const float* bg2  = (const float*)d_in[18];
  const float* Wc   = (const float*)d_in[19];
  const float* bc   = (const float*)d_in[20];
  float* out = (float*)d_out;

  // workspace (all 4-byte words; activations packed linear; weights frag-packed)
  uint32* xAp   = (uint32*)d_ws;                   // ROWS*D
  uint32* xBp   = xAp + (size_t)ROWS * D_;
  uint32* obp   = xBp + (size_t)ROWS * D_;
  uint32* bigp  = obp + (size_t)ROWS * D_;         // ROWS*FF (QKV 768 / FF1 1024)
  uint32* Wqkvp = bigp + (size_t)ROWS * FF_;       // L*768*256
  uint32* Wop   = Wqkvp + (size_t)L_ * 768 * 256;  // L*256*256
  uint32* W1p   = Wop   + (size_t)L_ * 256 * 256;  // L*1024*256
  uint32* W2p   = W1p   + (size_t)L_ * 1024 * 256; // L*256*1024
  uint32* Wg1p  = W2p   + (size_t)L_ * 256 * 1024; // 256*256
  float*  mem   = (float*)(Wg1p + 256 * 256);
  float*  qden  = mem + (size_t)M_ * D_;
  float*  sims  = qden + 64;
  int*    mask  = (int*)(sims + (size_t)B_ * M_);
  int*    slots = mask + ROWS;
  int*    cnt   = slots + ROWS;

  // pack weights into fragment-major layout (read-coalesced, once per call)
  for (int l = 0; l < L_; l++) {
    pack_wfrag<<<(768 * 256 / 4 + 255) / 256, 256, 0, stream>>>(
        Wqkv + (size_t)l * 768 * 256, Wqkvp + (size_t)l * 768 * 256, 768, 256);
    pack_wfrag<<<(256 * 256 / 4 + 255) / 256, 256, 0, stream>>>(
        Wo + (size_t)l * 256 * 256, Wop + (size_t)l * 256 * 256, 256, 256);
    pack_wfrag<<<(1024 * 256 / 4 + 255) / 256, 256, 0, stream>>>(
        W1 + (size_t)l * 1024 * 256, W1p + (size_t)l * 1024 * 256, 1024, 256);
    pack_wfrag<<<(256 * 1024 / 4 + 255) / 256, 256, 0, stream>>>(
        W2 + (size_t)l * 256 * 1024, W2p + (size_t)l * 256 * 1024, 256, 1024);
  }
  pack_wfrag<<<(256 * 256 / 4 + 255) / 256, 256, 0, stream>>>(Wg1, Wg1p, 256, 256);

  emb_kernel<<<ROWS / 4, 256, 0, stream>>>(ids, tok, pos, xAp);

  for (int l = 0; l < L_; l++) {
    gemm_mfma<0><<<768, 256, 0, stream>>>(
        xAp, Wqkvp + (size_t)l * 768 * 256, bqkv + l * 768, bigp, 256, 768, 6);
    attn_mfma<<<B_ * H_, 1024, 0, stream>>>(bigp, obp);
    // Wo GEMM fused with residual(xAp) + LN1 -> xBp
    gemm_ln<0><<<ROWS / 64, 512, 0, stream>>>(
        obp, Wop + (size_t)l * 256 * 256, bo + l * 256, xAp,
        ln1g + l * 256, ln1b + l * 256, nullptr, nullptr, xBp, nullptr, 256);
    gemm_mfma<1><<<1024, 256, 0, stream>>>(
        xBp, W1p + (size_t)l * 1024 * 256, b1 + l * 1024, bigp, 256, 1024, 8);
    // W2 GEMM fused with residual(xBp) + LN2 -> xAp
    gemm_ln<0><<<ROWS / 64, 512, 0, stream>>>(
        bigp, W2p + (size_t)l * 256 * 1024, b2 + l * 256, xBp,
        ln2g + l * 256, ln2b + l * 256, nullptr, nullptr, xAp, nullptr, 1024);
  }

  // gate MLP fused: mask[row] = (relu(h@Wg1^T+bg1) . Wg2 + bg2) > 0
  gemm_ln<1><<<ROWS / 64, 512, 0, stream>>>(
      xAp, Wg1p, bg1, nullptr, nullptr, nullptr, Wg2, bg2, nullptr, mask, 256);
  scan_kernel<<<1, 256, 0, stream>>>(mask, slots, cnt);
  (void)hipMemsetAsync(mem, 0, (size_t)M_ * D_ * sizeof(float), stream);
  scatter_kernel<<<ROWS / 4, 256, 0, stream>>>(xAp, slots, mem);

  qnorm_kernel<<<B_ / 4, 256, 0, stream>>>(xAp, qden);
  sims_kernel<<<M_ / 4, 256, 0, stream>>>(xAp, mem, qden, cnt, sims);
  topk_mix<<<B_, 256, 0, stream>>>(xAp, mem, sims, cnt, Wc, bc, out);
}

// Round 19
// 408.289 us; speedup vs baseline: 1.0196x; 1.0196x over previous
//
#include <hip/hip_runtime.h>
#include <math.h>

#define D_   256
#define H_   8
#define L_   2
#define FF_  1024
#define S_   512
#define B_   32
#define M_   4096
#define NC_  10
#define ROWS (B_*S_)   // 16384

typedef __attribute__((ext_vector_type(8))) short bf16x8;
typedef __attribute__((ext_vector_type(4))) float f32x4;
typedef unsigned int uint32;

__device__ __forceinline__ float wave_sum(float v) {
#pragma unroll
  for (int off = 1; off < 64; off <<= 1) v += __shfl_xor(v, off, 64);
  return v;
}

__device__ __forceinline__ unsigned short bf16_rne(float x) {
  unsigned int b = __float_as_uint(x);
  return (unsigned short)((b + 0x7FFFu + ((b >> 16) & 1u)) >> 16);
}
__device__ __forceinline__ float bf16_f(unsigned short h) {
  return __uint_as_float(((unsigned int)h) << 16);
}
// split x into hi/lo bf16, packed as hi | (lo<<16)
__device__ __forceinline__ uint32 pack_split(float x) {
  const unsigned short h = bf16_rne(x);
  const unsigned short l = bf16_rne(x - bf16_f(h));
  return (uint32)h | ((uint32)l << 16);
}
// reconstruct fp32 (hi+lo)
__device__ __forceinline__ float unsplit(uint32 p) {
  return __uint_as_float(p << 16) + __uint_as_float(p & 0xffff0000u);
}
// 4 packed elems -> 8B hi-quad + 8B lo-quad into LDS planes
__device__ __forceinline__ void unpack_store(unsigned short* Hq, unsigned short* Lq,
                                             int off, uint4 v) {
  uint2 hp, lp;
  hp.x = (v.x & 0xffffu) | (v.y << 16);
  hp.y = (v.z & 0xffffu) | (v.w << 16);
  lp.x = (v.x >> 16) | (v.y & 0xffff0000u);
  lp.y = (v.z >> 16) | (v.w & 0xffff0000u);
  *(uint2*)&Hq[off] = hp;
  *(uint2*)&Lq[off] = lp;
}
// b64-pair fragment load (rows at 72B/1032B stride)
__device__ __forceinline__ bf16x8 ld_frag(const unsigned short* p, int off) {
  union { uint2 u[2]; bf16x8 v; } x;
  x.u[0] = *(const uint2*)(p + off);
  x.u[1] = *(const uint2*)(p + off + 4);
  return x.v;
}

// ---------------- weight packing: fp32 -> packed split (vec4) ---------------
__global__ __launch_bounds__(256) void pack_f32(const float* __restrict__ src,
                                                uint32* __restrict__ dst, int n4) {
  const int i = blockIdx.x * 256 + threadIdx.x;
  if (i < n4) {
    const float4 v = ((const float4*)src)[i];
    uint4 o;
    o.x = pack_split(v.x); o.y = pack_split(v.y);
    o.z = pack_split(v.z); o.w = pack_split(v.w);
    ((uint4*)dst)[i] = o;
  }
}

// ---------------- embedding (packed only) -----------------------------------
__global__ __launch_bounds__(256) void emb_kernel(const int* __restrict__ ids,
                                                  const float* __restrict__ tok,
                                                  const float* __restrict__ pos,
                                                  uint32* __restrict__ xp) {
  const int row  = blockIdx.x * 4 + (threadIdx.x >> 6);
  const int lane = threadIdx.x & 63;
  const int id = ids[row];
  const int s  = row & (S_ - 1);
  const float4 t = *(const float4*)(tok + (size_t)id * D_ + lane * 4);
  const float4 p = *(const float4*)(pos + (size_t)s  * D_ + lane * 4);
  uint4 o;
  o.x = pack_split(t.x + p.x); o.y = pack_split(t.y + p.y);
  o.z = pack_split(t.z + p.z); o.w = pack_split(t.w + p.w);
  *(uint4*)(xp + (size_t)row * D_ + lane * 4) = o;
}

// ---- split-bf16 MFMA GEMM v2: 128x128 block, 4 waves of 64x64 -------------
#define LP 36
template<int RELU>
__global__ __launch_bounds__(256, 2) void gemm_mfma(const uint32* __restrict__ Ap,
                                                    const uint32* __restrict__ Bp,
                                                    const float* __restrict__ bias,
                                                    uint32* __restrict__ Cp,
                                                    int K, int N, int NX) {
  __shared__ __align__(16) unsigned short Ah[128 * LP];
  __shared__ __align__(16) unsigned short Al[128 * LP];
  __shared__ __align__(16) unsigned short Bh[128 * LP];
  __shared__ __align__(16) unsigned short Bl[128 * LP];

  const int q8 = gridDim.x >> 3;
  const int orig = (blockIdx.x & 7) * q8 + (blockIdx.x >> 3);
  const int by = orig / NX, bx = orig % NX;
  const int m0 = by * 128, n0 = bx * 128;

  const int tid  = threadIdx.x;
  const int lane = tid & 63;
  const int wid  = tid >> 6;        // 0..3
  const int wm = wid >> 1, wn = wid & 1;
  const int lrow  = lane & 15;
  const int khalf = (lane >> 4) * 8;

  const int srow = tid >> 3;        // 0..31 (+j*32)
  const int kq   = (tid & 7) << 2;
  const uint32* Aptr = Ap + (size_t)(m0 + srow) * K + kq;
  const uint32* Bptr = Bp + (size_t)(n0 + srow) * K + kq;

  f32x4 acc[4][4];
#pragma unroll
  for (int i = 0; i < 4; i++)
#pragma unroll
    for (int j = 0; j < 4; j++) acc[i][j] = (f32x4){0.f, 0.f, 0.f, 0.f};

  uint4 pa[4], pb[4];
#pragma unroll
  for (int j = 0; j < 4; j++) {
    pa[j] = *(const uint4*)(Aptr + (size_t)j * 32 * K);
    pb[j] = *(const uint4*)(Bptr + (size_t)j * 32 * K);
  }

  for (int k0 = 0; k0 < K; k0 += 32) {
    const int kn = (k0 + 32 < K) ? (k0 + 32) : k0;
    uint4 na[4], nb[4];
#pragma unroll
    for (int j = 0; j < 4; j++) {
      na[j] = *(const uint4*)(Aptr + (size_t)j * 32 * K + kn);
      nb[j] = *(const uint4*)(Bptr + (size_t)j * 32 * K + kn);
    }

    __syncthreads();
#pragma unroll
    for (int j = 0; j < 4; j++) {
      unpack_store(Ah, Al, (srow + j * 32) * LP + kq, pa[j]);
      unpack_store(Bh, Bl, (srow + j * 32) * LP + kq, pb[j]);
    }
    __syncthreads();

    bf16x8 ah[4], al[4], bh[4], bl[4];
#pragma unroll
    for (int f = 0; f < 4; f++) {
      const int rA = (wm * 64 + f * 16 + lrow) * LP + khalf;
      const int rB = (wn * 64 + f * 16 + lrow) * LP + khalf;
      ah[f] = ld_frag(Ah, rA);
      al[f] = ld_frag(Al, rA);
      bh[f] = ld_frag(Bh, rB);
      bl[f] = ld_frag(Bl, rB);
    }
#pragma unroll
    for (int fm = 0; fm < 4; fm++)
#pragma unroll
      for (int fn = 0; fn < 4; fn++) {
        acc[fm][fn] = __builtin_amdgcn_mfma_f32_16x16x32_bf16(ah[fm], bh[fn], acc[fm][fn], 0, 0, 0);
        acc[fm][fn] = __builtin_amdgcn_mfma_f32_16x16x32_bf16(ah[fm], bl[fn], acc[fm][fn], 0, 0, 0);
        acc[fm][fn] = __builtin_amdgcn_mfma_f32_16x16x32_bf16(al[fm], bh[fn], acc[fm][fn], 0, 0, 0);
      }
#pragma unroll
    for (int j = 0; j < 4; j++) { pa[j] = na[j]; pb[j] = nb[j]; }
  }

#pragma unroll
  for (int fm = 0; fm < 4; fm++)
#pragma unroll
    for (int fn = 0; fn < 4; fn++) {
      const int mrow = m0 + wm * 64 + fm * 16 + (lane >> 4) * 4;
      const int ncol = n0 + wn * 64 + fn * 16 + (lane & 15);
      const float bi = bias[ncol];
#pragma unroll
      for (int r = 0; r < 4; r++) {
        float v = acc[fm][fn][r] + bi;
        if (RELU) v = fmaxf(v, 0.f);
        Cp[(size_t)(mrow + r) * N + ncol] = pack_split(v);
      }
    }
}

// ---- fused full-row GEMM (N=256): 64x256 block, 8 waves of 32x64 ----------
// MODE 0: bias + residual(packed) + LayerNorm -> packed out.
// MODE 1: bias + ReLU + gate dot -> mask.
template<int MODE>
__global__ __launch_bounds__(512, 2) void gemm_ln(const uint32* __restrict__ Ap,
                                                  const uint32* __restrict__ Bp,
                                                  const float* __restrict__ bias,
                                                  const uint32* __restrict__ residP,
                                                  const float* __restrict__ g,
                                                  const float* __restrict__ beta,
                                                  const float* __restrict__ Wg2,
                                                  const float* __restrict__ bg2,
                                                  uint32* __restrict__ outP,
                                                  int* __restrict__ mask,
                                                  int K) {
  __shared__ __align__(16) unsigned short Ah[64 * LP];
  __shared__ __align__(16) unsigned short Al[64 * LP];
  __shared__ __align__(16) unsigned short Bh[256 * LP];
  __shared__ __align__(16) unsigned short Bl[256 * LP];
  __shared__ float psumS[4][64];
  __shared__ float psumQ[4][64];
  __shared__ float meanL[64];
  __shared__ float invL[64];

  const int q8 = gridDim.x >> 3;
  const int m0 = ((blockIdx.x & 7) * q8 + (blockIdx.x >> 3)) * 64;

  const int tid  = threadIdx.x;
  const int lane = tid & 63;
  const int wid  = tid >> 6;       // 0..7
  const int wm = wid >> 2, wn = wid & 3;
  const int lrow  = lane & 15;
  const int khalf = (lane >> 4) * 8;

  const int srow = tid >> 3;            // 0..63
  const int kq   = (tid & 7) << 2;
  const uint32* Aptr = Ap + (size_t)(m0 + srow) * K + kq;
  const uint32* Bptr = Bp + (size_t)srow * K + kq;    // rows srow + j*64

  f32x4 acc[2][4];
#pragma unroll
  for (int i = 0; i < 2; i++)
#pragma unroll
    for (int j = 0; j < 4; j++) acc[i][j] = (f32x4){0.f, 0.f, 0.f, 0.f};

  uint4 pa, pb[4];
  pa = *(const uint4*)Aptr;
#pragma unroll
  for (int j = 0; j < 4; j++) pb[j] = *(const uint4*)(Bptr + (size_t)j * 64 * K);

  for (int k0 = 0; k0 < K; k0 += 32) {
    const int kn = (k0 + 32 < K) ? (k0 + 32) : k0;
    uint4 na, nb[4];
    na = *(const uint4*)(Aptr + kn);
#pragma unroll
    for (int j = 0; j < 4; j++) nb[j] = *(const uint4*)(Bptr + (size_t)j * 64 * K + kn);

    __syncthreads();
    unpack_store(Ah, Al, srow * LP + kq, pa);
#pragma unroll
    for (int j = 0; j < 4; j++)
      unpack_store(Bh, Bl, (srow + j * 64) * LP + kq, pb[j]);
    __syncthreads();

    bf16x8 ah[2], al[2], bh[4], bl[4];
#pragma unroll
    for (int fm = 0; fm < 2; fm++) {
      const int r = (wm * 32 + fm * 16 + lrow) * LP + khalf;
      ah[fm] = ld_frag(Ah, r);
      al[fm] = ld_frag(Al, r);
    }
#pragma unroll
    for (int fn = 0; fn < 4; fn++) {
      const int r = (wn * 64 + fn * 16 + lrow) * LP + khalf;
      bh[fn] = ld_frag(Bh, r);
      bl[fn] = ld_frag(Bl, r);
    }
#pragma unroll
    for (int fm = 0; fm < 2; fm++)
#pragma unroll
      for (int fn = 0; fn < 4; fn++) {
        acc[fm][fn] = __builtin_amdgcn_mfma_f32_16x16x32_bf16(ah[fm], bh[fn], acc[fm][fn], 0, 0, 0);
        acc[fm][fn] = __builtin_amdgcn_mfma_f32_16x16x32_bf16(ah[fm], bl[fn], acc[fm][fn], 0, 0, 0);
        acc[fm][fn] = __builtin_amdgcn_mfma_f32_16x16x32_bf16(al[fm], bh[fn], acc[fm][fn], 0, 0, 0);
      }
    pa = na;
#pragma unroll
    for (int j = 0; j < 4; j++) pb[j] = nb[j];
  }

  // ---- epilogue: full row (256 cols) resident in block ----
  int cc[4];
  float bi[4];
#pragma unroll
  for (int fn = 0; fn < 4; fn++) {
    cc[fn] = wn * 64 + fn * 16 + (lane & 15);
    bi[fn] = bias[cc[fn]];
  }

  float vv[2][4][4];
  float rs[2][4], rq[2][4];

  if (MODE == 0) {
#pragma unroll
    for (int fm = 0; fm < 2; fm++)
#pragma unroll
      for (int r = 0; r < 4; r++) {
        const int row = m0 + wm * 32 + fm * 16 + (lane >> 4) * 4 + r;
        float s = 0.f, q = 0.f;
#pragma unroll
        for (int fn = 0; fn < 4; fn++) {
          const float rx = unsplit(residP[(size_t)row * 256 + cc[fn]]);
          const float a = acc[fm][fn][r] + bi[fn] + rx;
          vv[fm][fn][r] = a;
          s += a; q += a * a;
        }
        rs[fm][r] = s; rq[fm][r] = q;
      }
  } else {
    float wg[4];
#pragma unroll
    for (int fn = 0; fn < 4; fn++) wg[fn] = Wg2[cc[fn]];
#pragma unroll
    for (int fm = 0; fm < 2; fm++)
#pragma unroll
      for (int r = 0; r < 4; r++) {
        float s = 0.f;
#pragma unroll
        for (int fn = 0; fn < 4; fn++)
          s += fmaxf(acc[fm][fn][r] + bi[fn], 0.f) * wg[fn];
        rs[fm][r] = s;
      }
  }

#pragma unroll
  for (int off = 1; off < 16; off <<= 1) {
#pragma unroll
    for (int fm = 0; fm < 2; fm++)
#pragma unroll
      for (int r = 0; r < 4; r++) {
        rs[fm][r] += __shfl_xor(rs[fm][r], off, 64);
        if (MODE == 0) rq[fm][r] += __shfl_xor(rq[fm][r], off, 64);
      }
  }
  if ((lane & 15) == 0) {
#pragma unroll
    for (int fm = 0; fm < 2; fm++)
#pragma unroll
      for (int r = 0; r < 4; r++) {
        const int rloc = wm * 32 + fm * 16 + (lane >> 4) * 4 + r;
        psumS[wn][rloc] = rs[fm][r];
        if (MODE == 0) psumQ[wn][rloc] = rq[fm][r];
      }
  }
  __syncthreads();
  if (tid < 64) {
    float s = 0.f, q = 0.f;
#pragma unroll
    for (int w = 0; w < 4; w++) {
      s += psumS[w][tid];
      if (MODE == 0) q += psumQ[w][tid];
    }
    if (MODE == 0) {
      const float mean = s * (1.f / 256.f);
      const float var = q * (1.f / 256.f) - mean * mean;
      meanL[tid] = mean;
      invL[tid] = rsqrtf(var + 1e-5f);
    } else {
      mask[m0 + tid] = (s + bg2[0]) > 0.f ? 1 : 0;
    }
  }
  if (MODE == 0) {
    __syncthreads();
#pragma unroll
    for (int fm = 0; fm < 2; fm++)
#pragma unroll
      for (int r = 0; r < 4; r++) {
        const int rloc = wm * 32 + fm * 16 + (lane >> 4) * 4 + r;
        const int row = m0 + rloc;
        const float mu = meanL[rloc], iv = invL[rloc];
#pragma unroll
        for (int fn = 0; fn < 4; fn++) {
          const float y = (vv[fm][fn][r] - mu) * iv * g[cc[fn]] + beta[cc[fn]];
          outP[(size_t)row * 256 + cc[fn]] = pack_split(y);
        }
      }
  }
}

// ---------------- MFMA attention (monolithic stage, packed in/out) ----------
#define KP 36    // u16/row: 72B stride
#define VP 516   // u16/row: 1032B stride
__global__ __launch_bounds__(1024, 4) void attn_mfma(const uint32* __restrict__ qkv,
                                                     uint32* __restrict__ o) {
  __shared__ __align__(16) unsigned short Kh[512 * KP];
  __shared__ __align__(16) unsigned short Kl[512 * KP];
  __shared__ __align__(16) unsigned short Vth[32 * VP];
  __shared__ __align__(16) unsigned short Vtl[32 * VP];

  const int q8g = gridDim.x >> 3;                 // 32
  const int obh = (blockIdx.x & 7) * q8g + (blockIdx.x >> 3);
  const int b = obh >> 3, h = obh & 7;
  const int tid = threadIdx.x;
  const int lane = tid & 63;
  const int wv = tid >> 6;
  const uint32* base = qkv + (size_t)b * (S_ * 768) + h * 32;

  if (tid < 512) {
    const int slot = tid;
    const int s5 = slot & 31;
    const int orig = (slot & ~31) + 8 * ((s5 >> 2) & 3) + ((s5 >> 4) << 2) + (s5 & 3);
    const uint32* p = base + (size_t)orig * 768 + 256;
#pragma unroll
    for (int j = 0; j < 8; j++)
      unpack_store(Kh, Kl, slot * KP + j * 4, *(const uint4*)(p + j * 4));
  } else {
    const int u  = tid - 512;
    const int kp = u & 255;
    const int dg = (u >> 8) * 16;
    const uint32* p0 = base + (size_t)(2 * kp) * 768 + 512 + dg;
    const uint32* p1 = p0 + 768;
    union { uint4 u4[4]; uint32 w[16]; } a0, a1;
#pragma unroll
    for (int i = 0; i < 4; i++) {
      a0.u4[i] = *(const uint4*)(p0 + i * 4);
      a1.u4[i] = *(const uint4*)(p1 + i * 4);
    }
#pragma unroll
    for (int d = 0; d < 16; d++) {
      const uint32 w0 = a0.w[d], w1 = a1.w[d];
      *(uint32*)&Vth[(dg + d) * VP + 2 * kp] = (w0 & 0xffffu) | (w1 << 16);
      *(uint32*)&Vtl[(dg + d) * VP + 2 * kp] = (w0 >> 16) | (w1 & 0xffff0000u);
    }
  }

  const int q0 = wv * 32;
  bf16x8 qh[2], ql[2];
#pragma unroll
  for (int f = 0; f < 2; f++) {
    const uint32* qp = base + (size_t)(q0 + f * 16 + (lane & 15)) * 768 + ((lane >> 4) * 8);
    union { uint4 u4[2]; uint32 w[8]; } qu;
    qu.u4[0] = *(const uint4*)qp;
    qu.u4[1] = *(const uint4*)(qp + 4);
    bf16x8 vh, vl;
#pragma unroll
    for (int j = 0; j < 8; j++) {
      const float qf = unsplit(qu.w[j]);
      const float sv = qf * 0.17677669529663687f;
      const unsigned short hh = bf16_rne(sv);
      vh[j] = (short)hh;
      vl[j] = (short)bf16_rne(sv - bf16_f(hh));
    }
    qh[f] = vh; ql[f] = vl;
  }

  __syncthreads();

  f32x4 oacc[2][2];
#pragma unroll
  for (int i = 0; i < 2; i++)
#pragma unroll
    for (int j = 0; j < 2; j++) oacc[i][j] = (f32x4){0.f, 0.f, 0.f, 0.f};
  float lacc[2] = {0.f, 0.f};

  for (int kt = 0; kt < S_; kt += 32) {
    bf16x8 kah[2], kal[2];
#pragma unroll
    for (int u = 0; u < 2; u++) {
      const int off = (kt + u * 16 + (lane & 15)) * KP + ((lane >> 4) * 8);
      kah[u] = ld_frag(Kh, off);
      kal[u] = ld_frag(Kl, off);
    }
    bf16x8 vah[2], val[2];
#pragma unroll
    for (int df = 0; df < 2; df++) {
      const int off = (df * 16 + (lane & 15)) * VP + kt + ((lane >> 4) * 8);
      vah[df] = ld_frag(Vth, off);
      val[df] = ld_frag(Vtl, off);
    }
    f32x4 s[2][2];
#pragma unroll
    for (int u = 0; u < 2; u++)
#pragma unroll
      for (int f = 0; f < 2; f++) {
        f32x4 a = (f32x4){0.f, 0.f, 0.f, 0.f};
        a = __builtin_amdgcn_mfma_f32_16x16x32_bf16(kal[u], qh[f], a, 0, 0, 0);
        a = __builtin_amdgcn_mfma_f32_16x16x32_bf16(kah[u], ql[f], a, 0, 0, 0);
        a = __builtin_amdgcn_mfma_f32_16x16x32_bf16(kah[u], qh[f], a, 0, 0, 0);
        s[u][f] = a;
      }
#pragma unroll
    for (int f = 0; f < 2; f++) {
      union { uint32 w[4]; bf16x8 v; } ph, pl;
#pragma unroll
      for (int u = 0; u < 2; u++) {
        const float p0 = __expf(s[u][f][0]);
        const float p1 = __expf(s[u][f][1]);
        const float p2 = __expf(s[u][f][2]);
        const float p3 = __expf(s[u][f][3]);
        lacc[f] += (p0 + p1) + (p2 + p3);
        unsigned int h01, h23;
        asm volatile("v_cvt_pk_bf16_f32 %0, %1, %2" : "=v"(h01) : "v"(p0), "v"(p1));
        asm volatile("v_cvt_pk_bf16_f32 %0, %1, %2" : "=v"(h23) : "v"(p2), "v"(p3));
        const float r0 = p0 - __uint_as_float(h01 << 16);
        const float r1 = p1 - __uint_as_float(h01 & 0xffff0000u);
        const float r2 = p2 - __uint_as_float(h23 << 16);
        const float r3 = p3 - __uint_as_float(h23 & 0xffff0000u);
        unsigned int l01, l23;
        asm volatile("v_cvt_pk_bf16_f32 %0, %1, %2" : "=v"(l01) : "v"(r0), "v"(r1));
        asm volatile("v_cvt_pk_bf16_f32 %0, %1, %2" : "=v"(l23) : "v"(r2), "v"(r3));
        ph.w[u * 2 + 0] = h01;
        ph.w[u * 2 + 1] = h23;
        pl.w[u * 2 + 0] = l01;
        pl.w[u * 2 + 1] = l23;
      }
#pragma unroll
      for (int df = 0; df < 2; df++) {
        oacc[df][f] = __builtin_amdgcn_mfma_f32_16x16x32_bf16(val[df], ph.v, oacc[df][f], 0, 0, 0);
        oacc[df][f] = __builtin_amdgcn_mfma_f32_16x16x32_bf16(vah[df], pl.v, oacc[df][f], 0, 0, 0);
        oacc[df][f] = __builtin_amdgcn_mfma_f32_16x16x32_bf16(vah[df], ph.v, oacc[df][f], 0, 0, 0);
      }
    }
  }

#pragma unroll
  for (int f = 0; f < 2; f++) {
    lacc[f] += __shfl_xor(lacc[f], 16, 64);
    lacc[f] += __shfl_xor(lacc[f], 32, 64);
  }
#pragma unroll
  for (int f = 0; f < 2; f++) {
    const float inv = 1.f / lacc[f];
    const int q = q0 + f * 16 + (lane & 15);
    uint32* op = o + (size_t)(b * S_ + q) * D_ + h * 32;
#pragma unroll
    for (int df = 0; df < 2; df++) {
      const int dbase = df * 16 + (lane >> 4) * 4;
#pragma unroll
      for (int r = 0; r < 4; r++)
        op[dbase + r] = pack_split(oacc[df][f][r] * inv);
    }
  }
}

// -------- parallel prefix-scan over 16384 masks (sequential semantics) ------
__global__ __launch_bounds__(256) void scan_kernel(const int* __restrict__ mask,
                                                   int* __restrict__ slots,
                                                   int* __restrict__ countp) {
  __shared__ int wtot[4];
  const int tid = threadIdx.x;
  const int lane = tid & 63, wid = tid >> 6;
  const int base = tid * 64;
  int s = 0;
#pragma unroll 8
  for (int i = 0; i < 64; i++) s += mask[base + i];
  int inc = s;
#pragma unroll
  for (int off = 1; off < 64; off <<= 1) {
    const int t = __shfl_up(inc, off, 64);
    if (lane >= off) inc += t;
  }
  if (lane == 63) wtot[wid] = inc;
  __syncthreads();
  int woff = 0;
#pragma unroll
  for (int w = 0; w < 4; w++) woff += (w < wid) ? wtot[w] : 0;
  const int total = wtot[0] + wtot[1] + wtot[2] + wtot[3];
  if (tid == 0) countp[0] = total < M_ ? total : M_;
  int run = woff + inc - s;
  for (int i = 0; i < 64; i++) {
    const int r = base + i;
    const int mk = mask[r];
    slots[r] = (mk && run < M_) ? run : -1;
    run += mk;
  }
}

// ---------------- scatter selected rows into memory (packed h -> fp32 mem) --
__global__ __launch_bounds__(256) void scatter_kernel(const uint32* __restrict__ h,
                                                      const int* __restrict__ slots,
                                                      float* __restrict__ mem) {
  const int row  = blockIdx.x * 4 + (threadIdx.x >> 6);
  const int lane = threadIdx.x & 63;
  const int sl = slots[row];
  if (sl >= 0) {
    const uint4 p = *(const uint4*)(h + (size_t)row * D_ + lane * 4);
    float4 r;
    r.x = unsplit(p.x); r.y = unsplit(p.y);
    r.z = unsplit(p.z); r.w = unsplit(p.w);
    *(float4*)(mem + (size_t)sl * D_ + lane * 4) = r;
  }
}

// ---------------- query norms (one wave per batch row, packed h) ------------
__global__ __launch_bounds__(256) void qnorm_kernel(const uint32* __restrict__ h,
                                                    float* __restrict__ qden) {
  const int b    = blockIdx.x * 4 + (threadIdx.x >> 6);
  const int lane = threadIdx.x & 63;
  const uint4 p = *(const uint4*)(h + (size_t)b * S_ * D_ + lane * 4);
  const float x0 = unsplit(p.x), x1 = unsplit(p.y);
  const float x2 = unsplit(p.z), x3 = unsplit(p.w);
  float sq = x0 * x0 + x1 * x1 + x2 * x2 + x3 * x3;
  sq = wave_sum(sq);
  if (lane == 0) qden[b] = sqrtf(sq) + 1e-8f;
}

// ------- sims[b][r] for all 32 b: one wave per memory row r -----------------
__global__ __launch_bounds__(256) void sims_kernel(const uint32* __restrict__ h,
                                                   const float* __restrict__ mem,
                                                   const float* __restrict__ qden,
                                                   const int* __restrict__ countp,
                                                   float* __restrict__ sims) {
  __shared__ float cls[B_ * D_];
  __shared__ float qd[B_];
  const int tid = threadIdx.x;
  const int lane = tid & 63, wid = tid >> 6;
  for (int i = tid; i < B_ * D_ / 4; i += 256) {
    const int flat = i * 4;
    const int b = flat >> 8, d = flat & 255;
    const uint4 p = *(const uint4*)(h + (size_t)b * S_ * D_ + d);
    float4 r;
    r.x = unsplit(p.x); r.y = unsplit(p.y);
    r.z = unsplit(p.z); r.w = unsplit(p.w);
    *(float4*)&cls[flat] = r;
  }
  if (tid < B_) qd[tid] = qden[tid];
  __syncthreads();
  const int count = countp[0];
  const int r = blockIdx.x * 4 + wid;
  const float4 m4 = *(const float4*)(mem + (size_t)r * D_ + lane * 4);
  float sq = m4.x * m4.x + m4.y * m4.y + m4.z * m4.z + m4.w * m4.w;
  sq = wave_sum(sq);
  const float rn = sqrtf(sq) + 1e-8f;
  if (r < count) {
    for (int b = 0; b < B_; b++) {
      const float4 c4 = *(const float4*)&cls[b * D_ + lane * 4];
      float dt = m4.x * c4.x + m4.y * c4.y + m4.z * c4.z + m4.w * c4.w;
      dt = wave_sum(dt);
      if (lane == 0) sims[b * M_ + r] = dt / (qd[b] * rn);
    }
  } else if (lane == 0) {
    for (int b = 0; b < B_; b++) sims[b * M_ + r] = -1e9f;
  }
}

// ---------------- per-batch: top-4 (wave-parallel argmax), mix, classifier --
__global__ __launch_bounds__(256) void topk_mix(const uint32* __restrict__ h,
                                                const float* __restrict__ mem,
                                                const float* __restrict__ simsg,
                                                const int* __restrict__ countp,
                                                const float* __restrict__ Wc,
                                                const float* __restrict__ bc,
                                                float* __restrict__ out) {
  __shared__ float sims[M_];
  __shared__ float cls[D_];
  __shared__ float wv4[4];
  __shared__ int   wi4[4];
  __shared__ float aug[D_];
  __shared__ float tv[4];
  __shared__ int   tix[4];

  const int b = blockIdx.x, tid = threadIdx.x;
  const int lane = tid & 63, wid = tid >> 6;
  const int count = countp[0];

  for (int i = tid; i < M_; i += 256) sims[i] = simsg[b * M_ + i];
  cls[tid] = unsplit(h[(size_t)b * S_ * D_ + tid]);
  __syncthreads();

  for (int k = 0; k < 4; k++) {
    float bv = -INFINITY; int bi = 1 << 30;
#pragma unroll
    for (int rr = 0; rr < M_ / 256; rr++) {
      const int r = tid + rr * 256;
      const float v = sims[r];
      if (v > bv || (v == bv && r < bi)) { bv = v; bi = r; }
    }
#pragma unroll
    for (int off = 1; off < 64; off <<= 1) {
      const float ov = __shfl_xor(bv, off, 64);
      const int   oi = __shfl_xor(bi, off, 64);
      if (ov > bv || (ov == bv && oi < bi)) { bv = ov; bi = oi; }
    }
    if (lane == 0) { wv4[wid] = bv; wi4[wid] = bi; }
    __syncthreads();
    if (tid == 0) {
      float bb = wv4[0]; int bbi = wi4[0];
#pragma unroll
      for (int i = 1; i < 4; i++)
        if (wv4[i] > bb || (wv4[i] == bb && wi4[i] < bbi)) { bb = wv4[i]; bbi = wi4[i]; }
      tv[k] = bb; tix[k] = bbi; sims[bbi] = -INFINITY;
    }
    __syncthreads();
  }

  float w[4];
  {
    const float mx = tv[0];
    float ws = 0.f;
#pragma unroll
    for (int k = 0; k < 4; k++) { w[k] = expf(tv[k] - mx); ws += w[k]; }
    const float inv = 1.f / ws;
#pragma unroll
    for (int k = 0; k < 4; k++) w[k] *= inv;
  }

  {
    float mv = 0.f;
    if (count > 0) {
#pragma unroll
      for (int k = 0; k < 4; k++) mv = fmaf(w[k], mem[(size_t)tix[k] * D_ + tid], mv);
    }
    aug[tid] = cls[tid] + mv;
  }
  __syncthreads();

  const float4 a4 = *(const float4*)&aug[lane * 4];
  for (int c = wid; c < NC_; c += 4) {
    const float4 wc = *(const float4*)(Wc + (size_t)c * D_ + lane * 4);
    float dt = a4.x * wc.x + a4.y * wc.y + a4.z * wc.z + a4.w * wc.w;
    dt = wave_sum(dt);
    if (lane == 0) out[b * NC_ + c] = dt + bc[c];
  }
}

// ---------------- launcher ---------------------------------------------------
extern "C" void kernel_launch(void* const* d_in, const int* in_sizes, int n_in,
                              void* d_out, int out_size, void* d_ws, size_t ws_size,
                              hipStream_t stream) {
  const int*   ids  = (const int*)d_in[0];
  const float* tok  = (const float*)d_in[1];
  const float* pos  = (const float*)d_in[2];
  const float* Wqkv = (const float*)d_in[3];
  const float* bqkv = (const float*)d_in[4];
  const float* Wo   = (const float*)d_in[5];
  const float* bo   = (const float*)d_in[6];
  const float* ln1g = (const float*)d_in[7];
  const float* ln1b = (const float*)d_in[8];
  const float* W1   = (const float*)d_in[9];
  const float* b1   = (const float*)d_in[10];
  const float* W2   = (const float*)d_in[11];
  const float* b2   = (const float*)d_in[12];
  const float* ln2g = (const float*)d_in[13];
  const float* ln2b = (const float*)d_in[14];
  const float* Wg1  = (const float*)d_in[15];
  const float* bg1  = (const float*)d_in[16];
  const float* Wg2  = (const float*)d_in[17];
  const float* bg2  = (const float*)d_in[18];
  const float* Wc   = (const float*)d_in[19];
  const float* bc   = (const float*)d_in[20];
  float* out = (float*)d_out;

  // workspace (all 4-byte words; activations packed-only)
  uint32* xAp   = (uint32*)d_ws;                   // ROWS*D
  uint32* xBp   = xAp + (size_t)ROWS * D_;
  uint32* obp   = xBp + (size_t)ROWS * D_;
  uint32* bigp  = obp + (size_t)ROWS * D_;         // ROWS*FF (QKV 768 / FF1 1024)
  uint32* Wqkvp = bigp + (size_t)ROWS * FF_;       // L*768*256
  uint32* Wop   = Wqkvp + (size_t)L_ * 768 * 256;  // L*256*256
  uint32* W1p   = Wop   + (size_t)L_ * 256 * 256;  // L*1024*256
  uint32* W2p   = W1p   + (size_t)L_ * 1024 * 256; // L*256*1024
  uint32* Wg1p  = W2p   + (size_t)L_ * 256 * 1024; // 256*256
  float*  mem   = (float*)(Wg1p + 256 * 256);
  float*  qden  = mem + (size_t)M_ * D_;
  float*  sims  = qden + 64;
  int*    mask  = (int*)(sims + (size_t)B_ * M_);
  int*    slots = mask + ROWS;
  int*    cnt   = slots + ROWS;

  // pack weights once
  pack_f32<<<(L_ * 768 * 256 / 4 + 255) / 256, 256, 0, stream>>>(Wqkv, Wqkvp, L_ * 768 * 256 / 4);
  pack_f32<<<(L_ * 256 * 256 / 4 + 255) / 256, 256, 0, stream>>>(Wo, Wop, L_ * 256 * 256 / 4);
  pack_f32<<<(L_ * 1024 * 256 / 4 + 255) / 256, 256, 0, stream>>>(W1, W1p, L_ * 1024 * 256 / 4);
  pack_f32<<<(L_ * 256 * 1024 / 4 + 255) / 256, 256, 0, stream>>>(W2, W2p, L_ * 256 * 1024 / 4);
  pack_f32<<<(256 * 256 / 4 + 255) / 256, 256, 0, stream>>>(Wg1, Wg1p, 256 * 256 / 4);

  emb_kernel<<<ROWS / 4, 256, 0, stream>>>(ids, tok, pos, xAp);

  for (int l = 0; l < L_; l++) {
    gemm_mfma<0><<<768, 256, 0, stream>>>(
        xAp, Wqkvp + (size_t)l * 768 * 256, bqkv + l * 768, bigp, 256, 768, 6);
    attn_mfma<<<B_ * H_, 1024, 0, stream>>>(bigp, obp);
    // Wo GEMM fused with residual(xAp) + LN1 -> xBp
    gemm_ln<0><<<ROWS / 64, 512, 0, stream>>>(
        obp, Wop + (size_t)l * 256 * 256, bo + l * 256, xAp,
        ln1g + l * 256, ln1b + l * 256, nullptr, nullptr, xBp, nullptr, 256);
    gemm_mfma<1><<<1024, 256, 0, stream>>>(
        xBp, W1p + (size_t)l * 1024 * 256, b1 + l * 1024, bigp, 256, 1024, 8);
    // W2 GEMM fused with residual(xBp) + LN2 -> xAp
    gemm_ln<0><<<ROWS / 64, 512, 0, stream>>>(
        bigp, W2p + (size_t)l * 256 * 1024, b2 + l * 256, xBp,
        ln2g + l * 256, ln2b + l * 256, nullptr, nullptr, xAp, nullptr, 1024);
  }

  // gate MLP fused: mask[row] = (relu(h@Wg1^T+bg1) . Wg2 + bg2) > 0
  gemm_ln<1><<<ROWS / 64, 512, 0, stream>>>(
      xAp, Wg1p, bg1, nullptr, nullptr, nullptr, Wg2, bg2, nullptr, mask, 256);
  scan_kernel<<<1, 256, 0, stream>>>(mask, slots, cnt);
  (void)hipMemsetAsync(mem, 0, (size_t)M_ * D_ * sizeof(float), stream);
  scatter_kernel<<<ROWS / 4, 256, 0, stream>>>(xAp, slots, mem);

  qnorm_kernel<<<B_ / 4, 256, 0, stream>>>(xAp, qden);
  sims_kernel<<<M_ / 4, 256, 0, stream>>>(xAp, mem, qden, cnt, sims);
  topk_mix<<<B_, 256, 0, stream>>>(xAp, mem, sims, cnt, Wc, bc, out);
}